// Round 12
// baseline (606.294 us; speedup 1.0000x reference)
//
#include <hip/hip_runtime.h>

typedef __attribute__((ext_vector_type(8))) short bf16x8;
typedef __attribute__((ext_vector_type(4))) float f32x4;
typedef __attribute__((ext_vector_type(4))) unsigned u32x4;
typedef unsigned short u16;

#define SENT 0xC1C1C1C1u

// ---------- helpers ----------
__device__ __forceinline__ unsigned cvt_pk(float lo, float hi) {
  unsigned r;
  asm("v_cvt_pk_bf16_f32 %0, %1, %2" : "=v"(r) : "v"(lo), "v"(hi));
  return r;
}
__device__ __forceinline__ float bflo(unsigned d) { return __uint_as_float(d << 16); }
__device__ __forceinline__ float bfhi(unsigned d) { return __uint_as_float(d & 0xffff0000u); }
__device__ __forceinline__ float sigm(float x) { return 1.f / (1.f + __expf(-x)); }
__device__ __forceinline__ float tanhf_(float x) { return 1.f - 2.f / (__expf(2.f * x) + 1.f); }
// 4 bf16 (2 words) -> 4 fp8 bytes
__device__ __forceinline__ int pk4bf(unsigned w0, unsigned w1) {
  int r = __builtin_amdgcn_cvt_pk_fp8_f32(bflo(w0), bfhi(w0), 0, false);
  return __builtin_amdgcn_cvt_pk_fp8_f32(bflo(w1), bfhi(w1), r, true);
}
__device__ __forceinline__ int pk4f(float a, float b, float c, float d) {
  int r = __builtin_amdgcn_cvt_pk_fp8_f32(a, b, 0, false);
  return __builtin_amdgcn_cvt_pk_fp8_f32(c, d, r, true);
}

// ---------- K0: one-pass prep: emb->fp8 | Wih->fp8 | W_emit->bf16 | Whh->fp8 ----------
__global__ __launch_bounds__(256) void k_prep(const float* __restrict__ emb,
    const float* __restrict__ wf, const float* __restrict__ wb,
    const float* __restrict__ whf, const float* __restrict__ whb,
    const float* __restrict__ we,
    char* __restrict__ eb8, char* __restrict__ wih8, u16* __restrict__ weh,
    char* __restrict__ whh8) {
  int i4 = (blockIdx.x * 256 + threadIdx.x) * 4;
  if (i4 < 8204288) {
    const float* src; char* dst; int o;
    if (i4 < 7680000) { src = emb + i4; dst = eb8; o = i4; }
    else { int off = i4 - 7680000;
           src = (off < 262144) ? (wf + off) : (wb + off - 262144);
           dst = wih8; o = off; }
    f32x4 v = *(const f32x4*)src;
    *(int*)(dst + o) = pk4f(v[0], v[1], v[2], v[3]);
  } else if (i4 < 8212480) {
    int off = i4 - 8204288;          // 0..8191 (W_emit padded to 16 rows)
    int r = off >> 9, k = off & 511;
    f32x4 v = (r < 9) ? *(const f32x4*)(we + r * 512 + k) : (f32x4){0.f, 0.f, 0.f, 0.f};
    *(unsigned*)(weh + off) = cvt_pk(v[0], v[1]);
    *(unsigned*)(weh + off + 2) = cvt_pk(v[2], v[3]);
  } else {
    int off = i4 - 8212480;          // 0..524287 (Whh f|b)
    const float* src = (off < 262144) ? (whf + off) : (whb + off - 262144);
    f32x4 v = *(const f32x4*)src;
    *(int*)(whh8 + off) = pk4f(v[0], v[1], v[2], v[3]);
  }
}

// ---------- K1: fused BiLSTM, 2-chain interleave (A/B batch sub-slices) per block ----------
// 128 blocks = 8 js x (2 dir x 8 batch-pairs); per block LDS: Whh fp8 slice 33.8K + Wih fp8
// slice 33.8K + 2x h-stage fp8 4.35K + 2x x-stage fp8 4.35K + 2x gl f32 8.4K = 101.9 KB.
// While chain A's h-exchange (sentinel poll over MALL) is in flight, chain B computes -> the
// per-step RTT is mostly hidden under the other chain's stage+MFMA+epilogue.
__global__ __launch_bounds__(256) void k_lstm(
    const char* __restrict__ whh8, const char* __restrict__ wih8,
    const char* __restrict__ eb8, const int* __restrict__ ix,
    const float* __restrict__ bf_, const float* __restrict__ bb_,
    const float* __restrict__ h0f, const float* __restrict__ c0f,
    const float* __restrict__ h0b, const float* __restrict__ c0b,
    u16* __restrict__ hf, u16* __restrict__ hb) {
  __shared__ char wlh8[128 * 264];
  __shared__ char wli8[128 * 264];
  __shared__ __align__(16) char hs8[2][16 * 272];
  __shared__ __align__(16) char xs8[2][16 * 272];
  __shared__ float gl[2][16 * 132];
  int bid = blockIdx.x;
  int js = bid >> 4;                 // 0..7
  int rr = bid & 15;
  int dir = rr >> 3, bsp = rr & 7;
  u16* hout = dir ? hb : hf;
  int tid = threadIdx.x;
  // ---- stage weight slices (fp8, coalesced dword copy) ----
#pragma unroll
  for (int it = 0; it < 32; ++it) {
    int idx = it * 256 + tid;        // dword idx 0..8191
    int row = idx >> 6, cd = (idx & 63) * 4;
    int gate = (row >> 5) * 256 + js * 32 + (row & 31);
    long go = (long)(dir * 1024 + gate) * 256 + cd;
    *(int*)&wlh8[row * 264 + cd] = *(const int*)(whh8 + go);
    *(int*)&wli8[row * 264 + cd] = *(const int*)(wih8 + go);
  }
  int b_l = tid >> 4, jj = tid & 15;
  int jg0 = js * 32 + jj * 2;
  int bgA = bsp * 32 + b_l, bgB = bgA + 16;      // epilogue batch rows
  const float* bsrc = dir ? bb_ : bf_;
  float bI0 = bsrc[jg0],       bI1 = bsrc[jg0 + 1];
  float bF0 = bsrc[256 + jg0], bF1 = bsrc[257 + jg0];
  float bG0 = bsrc[512 + jg0], bG1 = bsrc[513 + jg0];
  float bO0 = bsrc[768 + jg0], bO1 = bsrc[769 + jg0];
  const float* c0 = dir ? c0b : c0f;
  float cvA0 = c0[bgA * 256 + jg0], cvA1 = c0[bgA * 256 + jg0 + 1];
  float cvB0 = c0[bgB * 256 + jg0], cvB1 = c0[bgB * 256 + jg0 + 1];
  int w = tid >> 6, l = tid & 63, la = l & 15, lk = (l >> 4) * 8;
  int srow = tid >> 4, scol = (tid & 15) * 16;
  int sgA = bsp * 32 + srow, sgB = sgA + 16;     // staging batch rows
  const float* h0 = dir ? h0b : h0f;
  const int* ixA = ix + sgA * 128;
  const int* ixB = ix + sgB * 128;
  int t0 = dir ? 127 : 0;
  u32x4 aRA = *(const u32x4*)(eb8 + (long)ixA[t0] * 256 + scol);
  u32x4 aRB = *(const u32x4*)(eb8 + (long)ixB[t0] * 256 + scol);
  __syncthreads();
  for (int sl = 0; sl < 128; ++sl) {
    int t_io = dir ? 127 - sl : sl;
    int tp = dir ? t_io + 1 : t_io - 1;
    // ================= phase A =================
    *(u32x4*)&xs8[0][srow * 272 + scol] = aRA;
    {
      int q0, q1, q2, q3;
      if (sl == 0) {
        const float* p = h0 + sgA * 256 + scol;
        f32x4 v0 = *(const f32x4*)p, v1 = *(const f32x4*)(p + 4);
        f32x4 v2 = *(const f32x4*)(p + 8), v3 = *(const f32x4*)(p + 12);
        q0 = pk4f(v0[0], v0[1], v0[2], v0[3]); q1 = pk4f(v1[0], v1[1], v1[2], v1[3]);
        q2 = pk4f(v2[0], v2[1], v2[2], v2[3]); q3 = pk4f(v3[0], v3[1], v3[2], v3[3]);
      } else {
        const u16* p = hout + ((long)sgA * 128 + tp) * 256 + scol;
        u32x4 r0, r1; int guard = 0; bool ok;
        do {
          asm volatile(
            "global_load_dwordx4 %0, %2, off sc0 sc1\n\t"
            "global_load_dwordx4 %1, %2, off offset:16 sc0 sc1\n\t"
            "s_waitcnt vmcnt(0)"
            : "=v"(r0), "=v"(r1) : "v"(p) : "memory");
          ok = (r0[0] != SENT) & (r0[1] != SENT) & (r0[2] != SENT) & (r0[3] != SENT)
             & (r1[0] != SENT) & (r1[1] != SENT) & (r1[2] != SENT) & (r1[3] != SENT);
        } while (__builtin_expect(!ok, 0) && ++guard < (1 << 22));
        q0 = pk4bf(r0[0], r0[1]); q1 = pk4bf(r0[2], r0[3]);
        q2 = pk4bf(r1[0], r1[1]); q3 = pk4bf(r1[2], r1[3]);
      }
      int4 qq = make_int4(q0, q1, q2, q3);
      *(int4*)&hs8[0][srow * 272 + scol] = qq;
    }
    __syncthreads();
    {
      f32x4 a0 = (f32x4){0.f, 0.f, 0.f, 0.f}, a1 = (f32x4){0.f, 0.f, 0.f, 0.f};
#pragma unroll
      for (int ks = 0; ks < 8; ++ks) {
        int k = ks * 32 + lk;
        long xv = *(const long*)&xs8[0][la * 272 + k];
        long hv = *(const long*)&hs8[0][la * 272 + k];
        int r0_ = w * 32 + la, r1_ = r0_ + 16;
        long wi0 = *(const long*)&wli8[r0_ * 264 + k];
        long wh0 = *(const long*)&wlh8[r0_ * 264 + k];
        long wi1 = *(const long*)&wli8[r1_ * 264 + k];
        long wh1 = *(const long*)&wlh8[r1_ * 264 + k];
        a0 = __builtin_amdgcn_mfma_f32_16x16x32_fp8_fp8(xv, wi0, a0, 0, 0, 0);
        a0 = __builtin_amdgcn_mfma_f32_16x16x32_fp8_fp8(hv, wh0, a0, 0, 0, 0);
        a1 = __builtin_amdgcn_mfma_f32_16x16x32_fp8_fp8(xv, wi1, a1, 0, 0, 0);
        a1 = __builtin_amdgcn_mfma_f32_16x16x32_fp8_fp8(hv, wh1, a1, 0, 0, 0);
      }
#pragma unroll
      for (int r = 0; r < 4; ++r) {
        gl[0][((l >> 4) * 4 + r) * 132 + w * 32 + la] = a0[r];
        gl[0][((l >> 4) * 4 + r) * 132 + w * 32 + 16 + la] = a1[r];
      }
    }
    __syncthreads();
    {
      float hv0, hv1;
      {
        int jl = jj * 2;
        float gi = gl[0][b_l * 132 + jl]      + bI0;
        float gf = gl[0][b_l * 132 + 32 + jl] + bF0;
        float gg = gl[0][b_l * 132 + 64 + jl] + bG0;
        float go = gl[0][b_l * 132 + 96 + jl] + bO0;
        float c = sigm(gf) * cvA0 + sigm(gi) * tanhf_(gg);
        cvA0 = c; hv0 = sigm(go) * tanhf_(c);
      }
      {
        int jl = jj * 2 + 1;
        float gi = gl[0][b_l * 132 + jl]      + bI1;
        float gf = gl[0][b_l * 132 + 32 + jl] + bF1;
        float gg = gl[0][b_l * 132 + 64 + jl] + bG1;
        float go = gl[0][b_l * 132 + 96 + jl] + bO1;
        float c = sigm(gf) * cvA1 + sigm(gi) * tanhf_(gg);
        cvA1 = c; hv1 = sigm(go) * tanhf_(c);
      }
      __hip_atomic_store((unsigned*)(hout + ((long)bgA * 128 + t_io) * 256 + jg0),
                         cvt_pk(hv0, hv1), __ATOMIC_RELAXED, __HIP_MEMORY_SCOPE_AGENT);
      if (sl < 127) {
        int tN = dir ? 126 - sl : sl + 1;
        aRA = *(const u32x4*)(eb8 + (long)ixA[tN] * 256 + scol);
      }
    }
    // ================= phase B =================
    *(u32x4*)&xs8[1][srow * 272 + scol] = aRB;
    {
      int q0, q1, q2, q3;
      if (sl == 0) {
        const float* p = h0 + sgB * 256 + scol;
        f32x4 v0 = *(const f32x4*)p, v1 = *(const f32x4*)(p + 4);
        f32x4 v2 = *(const f32x4*)(p + 8), v3 = *(const f32x4*)(p + 12);
        q0 = pk4f(v0[0], v0[1], v0[2], v0[3]); q1 = pk4f(v1[0], v1[1], v1[2], v1[3]);
        q2 = pk4f(v2[0], v2[1], v2[2], v2[3]); q3 = pk4f(v3[0], v3[1], v3[2], v3[3]);
      } else {
        const u16* p = hout + ((long)sgB * 128 + tp) * 256 + scol;
        u32x4 r0, r1; int guard = 0; bool ok;
        do {
          asm volatile(
            "global_load_dwordx4 %0, %2, off sc0 sc1\n\t"
            "global_load_dwordx4 %1, %2, off offset:16 sc0 sc1\n\t"
            "s_waitcnt vmcnt(0)"
            : "=v"(r0), "=v"(r1) : "v"(p) : "memory");
          ok = (r0[0] != SENT) & (r0[1] != SENT) & (r0[2] != SENT) & (r0[3] != SENT)
             & (r1[0] != SENT) & (r1[1] != SENT) & (r1[2] != SENT) & (r1[3] != SENT);
        } while (__builtin_expect(!ok, 0) && ++guard < (1 << 22));
        q0 = pk4bf(r0[0], r0[1]); q1 = pk4bf(r0[2], r0[3]);
        q2 = pk4bf(r1[0], r1[1]); q3 = pk4bf(r1[2], r1[3]);
      }
      int4 qq = make_int4(q0, q1, q2, q3);
      *(int4*)&hs8[1][srow * 272 + scol] = qq;
    }
    __syncthreads();
    {
      f32x4 a0 = (f32x4){0.f, 0.f, 0.f, 0.f}, a1 = (f32x4){0.f, 0.f, 0.f, 0.f};
#pragma unroll
      for (int ks = 0; ks < 8; ++ks) {
        int k = ks * 32 + lk;
        long xv = *(const long*)&xs8[1][la * 272 + k];
        long hv = *(const long*)&hs8[1][la * 272 + k];
        int r0_ = w * 32 + la, r1_ = r0_ + 16;
        long wi0 = *(const long*)&wli8[r0_ * 264 + k];
        long wh0 = *(const long*)&wlh8[r0_ * 264 + k];
        long wi1 = *(const long*)&wli8[r1_ * 264 + k];
        long wh1 = *(const long*)&wlh8[r1_ * 264 + k];
        a0 = __builtin_amdgcn_mfma_f32_16x16x32_fp8_fp8(xv, wi0, a0, 0, 0, 0);
        a0 = __builtin_amdgcn_mfma_f32_16x16x32_fp8_fp8(hv, wh0, a0, 0, 0, 0);
        a1 = __builtin_amdgcn_mfma_f32_16x16x32_fp8_fp8(xv, wi1, a1, 0, 0, 0);
        a1 = __builtin_amdgcn_mfma_f32_16x16x32_fp8_fp8(hv, wh1, a1, 0, 0, 0);
      }
#pragma unroll
      for (int r = 0; r < 4; ++r) {
        gl[1][((l >> 4) * 4 + r) * 132 + w * 32 + la] = a0[r];
        gl[1][((l >> 4) * 4 + r) * 132 + w * 32 + 16 + la] = a1[r];
      }
    }
    __syncthreads();
    {
      float hv0, hv1;
      {
        int jl = jj * 2;
        float gi = gl[1][b_l * 132 + jl]      + bI0;
        float gf = gl[1][b_l * 132 + 32 + jl] + bF0;
        float gg = gl[1][b_l * 132 + 64 + jl] + bG0;
        float go = gl[1][b_l * 132 + 96 + jl] + bO0;
        float c = sigm(gf) * cvB0 + sigm(gi) * tanhf_(gg);
        cvB0 = c; hv0 = sigm(go) * tanhf_(c);
      }
      {
        int jl = jj * 2 + 1;
        float gi = gl[1][b_l * 132 + jl]      + bI1;
        float gf = gl[1][b_l * 132 + 32 + jl] + bF1;
        float gg = gl[1][b_l * 132 + 64 + jl] + bG1;
        float go = gl[1][b_l * 132 + 96 + jl] + bO1;
        float c = sigm(gf) * cvB1 + sigm(gi) * tanhf_(gg);
        cvB1 = c; hv1 = sigm(go) * tanhf_(c);
      }
      __hip_atomic_store((unsigned*)(hout + ((long)bgB * 128 + t_io) * 256 + jg0),
                         cvt_pk(hv0, hv1), __ATOMIC_RELAXED, __HIP_MEMORY_SCOPE_AGENT);
      if (sl < 127) {
        int tN = dir ? 126 - sl : sl + 1;
        aRB = *(const u32x4*)(eb8 + (long)ixB[tN] * 256 + scol);
      }
    }
  }
}

// ---------- K3: emission (also zero-inits out[0] for the tail's atomic loss sum) ----------
__global__ __launch_bounds__(256) void k_emis(const u16* __restrict__ hfb, const u16* __restrict__ hbb,
    const u16* __restrict__ weh, const float* __restrict__ bemit, float* __restrict__ emis,
    float* __restrict__ out) {
  if (blockIdx.x == 0 && threadIdx.x == 0) out[0] = 0.f;
  int w = threadIdx.x >> 6, l = threadIdx.x & 63;
  int la = l & 15, lk = (l >> 4) * 8;
  long m0 = (long)blockIdx.x * 64 + w * 16;
  long am = m0 + la;
  f32x4 acc = (f32x4){0.f, 0.f, 0.f, 0.f};
#pragma unroll
  for (int ks = 0; ks < 16; ++ks) {
    int k = ks * 32 + lk;
    const u16* src = (k < 256) ? (hfb + am * 256 + k) : (hbb + am * 256 + (k - 256));
    bf16x8 ah = *(const bf16x8*)src;
    bf16x8 bh = *(const bf16x8*)(weh + la * 512 + k);
    acc = __builtin_amdgcn_mfma_f32_16x16x32_bf16(ah, bh, acc, 0, 0, 0);
  }
  int kout = la;
  float bias = (kout < 9) ? bemit[kout] : 0.f;
  long mr = m0 + (l >> 4) * 4;
#pragma unroll
  for (int r = 0; r < 4; ++r)
    emis[(mr + r) * 16 + kout] = acc[r] + bias;
}

// ---------- K4: fused tail. Blocks 0-15: CRF -> atomicAdd loss. 16-31: Viterbi + backtrace. ----------
__global__ __launch_bounds__(256) void k_tail(const float* __restrict__ emis, const int* __restrict__ ixin,
    const int* __restrict__ label, const float* __restrict__ startt, const float* __restrict__ endt,
    const float* __restrict__ trans, float* __restrict__ out) {
  __shared__ float al_s[16][16];
  __shared__ float tr_s[9][16];
  __shared__ float num_s[16];
  __shared__ float red_s[16];
  __shared__ unsigned char bpl[16 * 127 * 16];
  int tid = threadIdx.x, bl = tid >> 4, k = tid & 15;
  int bid = blockIdx.x;
  if (bl < 9) tr_s[bl][k] = (k < 9) ? trans[bl * 9 + k] : 0.f;
  if (bid < 16) {
    int b = bid * 16 + bl;
    float a = 0.f, num = 0.f;
    int lastlab = 0;
    if (k < 9) a = startt[k] + emis[((long)b * 128) * 16 + k];
    al_s[bl][k] = a;
    if (k == 9) {
      int l0 = label[b * 128];
      num = startt[l0] + emis[((long)b * 128) * 16 + l0];
      lastlab = l0;
    }
    __syncthreads();
    for (int t = 1; t < 128; ++t) {
      bool msk = ixin[b * 128 + t] != 0;
      float anew = a;
      if (k < 9) {
        float mx = -1e30f;
#pragma unroll
        for (int j = 0; j < 9; ++j) mx = fmaxf(mx, al_s[bl][j] + tr_s[j][k]);
        float ss = 0.f;
#pragma unroll
        for (int j = 0; j < 9; ++j) ss += __expf(al_s[bl][j] + tr_s[j][k] - mx);
        anew = mx + __logf(ss) + emis[((long)b * 128 + t) * 16 + k];
        if (!msk) anew = a;
      } else if (k == 9 && msk) {
        int lt = label[b * 128 + t];
        num += tr_s[lastlab][lt] + emis[((long)b * 128 + t) * 16 + lt];
        lastlab = lt;
      }
      __syncthreads();
      if (k < 9) { a = anew; al_s[bl][k] = a; }
      __syncthreads();
    }
    if (k == 9) num_s[bl] = num + endt[lastlab];
    __syncthreads();
    if (k == 0) {
      float mx = -1e30f;
#pragma unroll
      for (int j = 0; j < 9; ++j) mx = fmaxf(mx, al_s[bl][j] + endt[j]);
      float ss = 0.f;
#pragma unroll
      for (int j = 0; j < 9; ++j) ss += __expf(al_s[bl][j] + endt[j] - mx);
      red_s[bl] = (mx + __logf(ss)) - num_s[bl];
    }
    __syncthreads();
    if (tid == 0) {
      float s = 0.f;
      for (int i = 0; i < 16; ++i) s += red_s[i];
      atomicAdd(out, s);
    }
  } else {
    int vb = bid - 16;
    int b = vb * 16 + bl;
    float v = -1e30f;
    if (k < 9) v = startt[k] + emis[((long)b * 128) * 16 + k];
    al_s[bl][k] = v;
    __syncthreads();
    for (int t = 1; t < 128; ++t) {
      float vnew = v;
      if (k < 9) {
        float best = -1e30f; int bi = 0;
#pragma unroll
        for (int j = 0; j < 9; ++j) {
          float tot = al_s[bl][j] + tr_s[j][k];
          if (tot > best) { best = tot; bi = j; }
        }
        vnew = best + emis[((long)b * 128 + t) * 16 + k];
        bpl[(bl * 127 + (t - 1)) * 16 + k] = (unsigned char)bi;
      }
      __syncthreads();
      if (k < 9) { v = vnew; al_s[bl][k] = v; }
      __syncthreads();
    }
    if (tid < 16) {
      int bb = vb * 16 + tid;
      float best = -1e30f; int tag = 0;
#pragma unroll
      for (int j = 0; j < 9; ++j) {
        float vv = al_s[tid][j] + endt[j];
        if (vv > best) { best = vv; tag = j; }
      }
      out[1 + bb * 128 + 127] = (float)tag;
      for (int t = 127; t >= 1; --t) {
        tag = bpl[(tid * 127 + (t - 1)) * 16 + tag];
        out[1 + bb * 128 + t - 1] = (float)tag;
      }
    }
  }
}

__global__ void k_sent(float* out) { out[0] = -1.0e6f; }

// ---------- launch ----------
extern "C" void kernel_launch(void* const* d_in, const int* in_sizes, int n_in,
                              void* d_out, int out_size, void* d_ws, size_t ws_size,
                              hipStream_t stream) {
  const int* in_x    = (const int*)d_in[0];
  const int* label   = (const int*)d_in[1];
  const float* emb   = (const float*)d_in[2];
  const float* Wih_f = (const float*)d_in[3];
  const float* Whh_f = (const float*)d_in[4];
  const float* b_f   = (const float*)d_in[5];
  const float* Wih_b = (const float*)d_in[6];
  const float* Whh_b = (const float*)d_in[7];
  const float* b_b   = (const float*)d_in[8];
  const float* W_emit= (const float*)d_in[9];
  const float* b_emit= (const float*)d_in[10];
  const float* start_t=(const float*)d_in[11];
  const float* end_t = (const float*)d_in[12];
  const float* trans = (const float*)d_in[13];
  const float* h0f   = (const float*)d_in[14];
  const float* c0f   = (const float*)d_in[15];
  const float* h0b   = (const float*)d_in[16];
  const float* c0b   = (const float*)d_in[17];
  (void)in_sizes; (void)n_in; (void)out_size;

  auto align = [](size_t x) { return (x + 255) & ~(size_t)255; };
  char* ws = (char*)d_ws;
  size_t o = 0;
  auto alloc = [&](size_t sz) { size_t r = o; o += (sz + 255) & ~(size_t)255; return r; };
  size_t need = align(32768L * 256 * 2) * 2 + align(30000L * 256) + align(2048L * 256) * 2
              + align(16L * 512 * 2) + align(32768L * 16 * 4);
  if (need > ws_size) { k_sent<<<1, 1, 0, stream>>>((float*)d_out); return; }

  u16* hf    = (u16*)(ws + alloc(32768L * 256 * 2));
  u16* hb    = (u16*)(ws + alloc(32768L * 256 * 2));
  char* eb8  = (char*)(ws + alloc(30000L * 256));
  char* wih8 = (char*)(ws + alloc(2048L * 256));
  char* whh8 = (char*)(ws + alloc(2048L * 256));
  u16* weh   = (u16*)(ws + alloc(16L * 512 * 2));
  float* emis= (float*)(ws + alloc(32768L * 16 * 4));

  // sentinel-init h buffers (0xC1C1 bf16 == -24.1, impossible for tanh*sigm output);
  // re-poisoned every call so graph replays never see stale h as "ready".
  hipMemsetAsync(hf, 0xC1, 32768L * 256 * 2, stream);
  hipMemsetAsync(hb, 0xC1, 32768L * 256 * 2, stream);
  k_prep<<<8532, 256, 0, stream>>>(emb, Wih_f, Wih_b, Whh_f, Whh_b, W_emit,
                                   eb8, wih8, weh, whh8);
  k_lstm<<<128, 256, 0, stream>>>(whh8, wih8, eb8, in_x, b_f, b_b,
                                  h0f, c0f, h0b, c0b, hf, hb);
  k_emis<<<512, 256, 0, stream>>>(hf, hb, weh, b_emit, emis, (float*)d_out);
  k_tail<<<32, 256, 0, stream>>>(emis, in_x, label, start_t, end_t, trans, (float*)d_out);
}

// Round 13
// 580.879 us; speedup vs baseline: 1.0438x; 1.0438x over previous
//
#include <hip/hip_runtime.h>

typedef __attribute__((ext_vector_type(8))) short bf16x8;
typedef __attribute__((ext_vector_type(4))) float f32x4;
typedef __attribute__((ext_vector_type(4))) unsigned u32x4;
typedef unsigned short u16;

#define SENT16 0xC1C1u

// ---------- helpers ----------
__device__ __forceinline__ u16 f2bf(float f) {
  union { float f; unsigned u; } v; v.f = f;
  unsigned r = v.u + 0x7fffu + ((v.u >> 16) & 1u);
  return (u16)(r >> 16);
}
__device__ __forceinline__ unsigned cvt_pk(float lo, float hi) {
  unsigned r;
  asm("v_cvt_pk_bf16_f32 %0, %1, %2" : "=v"(r) : "v"(lo), "v"(hi));
  return r;
}
__device__ __forceinline__ float sigm(float x) { return 1.f / (1.f + __expf(-x)); }
__device__ __forceinline__ float tanhf_(float x) { return 1.f - 2.f / (__expf(2.f * x) + 1.f); }
__device__ __forceinline__ int pk4f(float a, float b, float c, float d) {
  int r = __builtin_amdgcn_cvt_pk_fp8_f32(a, b, 0, false);
  return __builtin_amdgcn_cvt_pk_fp8_f32(c, d, r, true);
}
__device__ __forceinline__ bool half_ok(unsigned v) {
  return ((v & 0xFFFFu) != SENT16) & ((v >> 16) != SENT16);
}

// ---------- K0: one-pass prep: emb -> fp8 | Wih -> fp8 | W_emit -> bf16 ----------
__global__ __launch_bounds__(256) void k_prep(const float* __restrict__ emb,
    const float* __restrict__ wf, const float* __restrict__ wb, const float* __restrict__ we,
    char* __restrict__ eb8, char* __restrict__ wih8, u16* __restrict__ weh) {
  int i4 = (blockIdx.x * 256 + threadIdx.x) * 4;
  if (i4 < 8204288) {
    const float* src; char* dst; int o;
    if (i4 < 7680000) { src = emb + i4; dst = eb8; o = i4; }
    else { int off = i4 - 7680000;
           src = (off < 262144) ? (wf + off) : (wb + off - 262144);
           dst = wih8; o = off; }
    f32x4 v = *(const f32x4*)src;
    *(int*)(dst + o) = pk4f(v[0], v[1], v[2], v[3]);
  } else {
    int off = i4 - 8204288;          // 0..8191 (W_emit padded to 16 rows)
    int r = off >> 9, k = off & 511;
    f32x4 v = (r < 9) ? *(const f32x4*)(we + r * 512 + k) : (f32x4){0.f, 0.f, 0.f, 0.f};
    *(unsigned*)(weh + off) = cvt_pk(v[0], v[1]);
    *(unsigned*)(weh + off + 2) = cvt_pk(v[2], v[3]);
  }
}

// ---------- K1: fused BiLSTM, sentinel dataflow; lane-local epilogue (j*4+q row order) ----------
// 256 blocks = 2 dir x 16 bs x 8 js. LDS rows ordered j_loc*4+q so a lane's 4 MFMA acc values
// are the i,f,g,o gates of one (j,b): epilogue in registers, no gate exchange, 1 barrier/step.
#define LW 264
__global__ __launch_bounds__(256) void k_lstm(
    const float* __restrict__ whh_f, const float* __restrict__ whh_b,
    const char* __restrict__ wih8, const char* __restrict__ eb8,
    const int* __restrict__ ix,
    const float* __restrict__ bf_, const float* __restrict__ bb_,
    const float* __restrict__ h0f, const float* __restrict__ c0f,
    const float* __restrict__ h0b, const float* __restrict__ c0b,
    u16* __restrict__ hf, u16* __restrict__ hb) {
  __shared__ u16 wlh[128 * LW];              // Whh slice bf16, rows j*4+q
  __shared__ char wli8[128 * 264];           // Wih slice fp8, rows j*4+q
  __shared__ u16 hst[2][16 * LW];            // h(t-1) stage bf16, double-buffered
  int bid = blockIdx.x;
  int js = (bid >> 3) & 7;
  int G = ((bid >> 6) << 3) | (bid & 7);
  int dir = G >> 4, bs = G & 15;
  const float* whh = dir ? whh_b : whh_f;
  u16* hout = dir ? hb : hf;
  int tid = threadIdx.x;
  // stage weight slices, row i = j_loc*4+q  ->  source gate row q*256 + js*32 + j_loc
  for (int i = 0; i < 128; ++i) {
    int jl = i >> 2, q = i & 3;
    int gate = q * 256 + js * 32 + jl;
    wlh[i * LW + tid] = f2bf(whh[gate * 256 + tid]);
    wli8[i * 264 + tid] = wih8[(dir * 1024 + gate) * 256 + tid];
  }
  int w = tid >> 6, l = tid & 63;
  int lb = l & 15, lk8 = (l >> 4) * 8;
  // lane-local output identity: batch b = lb, j0 = js*32 + w*8 + (l>>4), j1 = j0 + 4
  int b_g = bs * 16 + lb;
  int j0 = js * 32 + w * 8 + (l >> 4);
  int j1 = j0 + 4;
  const float* bsrc = dir ? bb_ : bf_;
  f32x4 bv0 = { bsrc[j0], bsrc[256 + j0], bsrc[512 + j0], bsrc[768 + j0] };
  f32x4 bv1 = { bsrc[j1], bsrc[256 + j1], bsrc[512 + j1], bsrc[768 + j1] };
  const float* c0 = dir ? c0b : c0f;
  float cv0 = c0[b_g * 256 + j0];
  float cv1 = c0[b_g * 256 + j1];
  int srow = tid >> 4, scol = (tid & 15) * 16;
  const float* h0 = dir ? h0b : h0f;
  // x fragment prefetch for step 0 (lane reads row b = lb of the x tile)
  long xb[8];
  {
    int t0 = dir ? 127 : 0;
    long xrow = (long)ix[b_g * 128 + t0] * 256;
#pragma unroll
    for (int ks = 0; ks < 8; ++ks) xb[ks] = *(const long*)(eb8 + xrow + ks * 32 + lk8);
  }
  __syncthreads();
  int cur = 0;
  for (int sl = 0; sl < 128; ++sl) {
    int t_io = dir ? 127 - sl : sl;
    // ---- stage h(t-1) into hst[cur] ----
    u16* hd = &hst[cur][srow * LW + scol];
    if (sl == 0) {
      const float* p = h0 + (bs * 16 + srow) * 256 + scol;
      f32x4 v0 = *(const f32x4*)p, v1 = *(const f32x4*)(p + 4);
      f32x4 v2 = *(const f32x4*)(p + 8), v3 = *(const f32x4*)(p + 12);
      u32x4 qa, qb;
      qa[0] = cvt_pk(v0[0], v0[1]); qa[1] = cvt_pk(v0[2], v0[3]);
      qa[2] = cvt_pk(v1[0], v1[1]); qa[3] = cvt_pk(v1[2], v1[3]);
      qb[0] = cvt_pk(v2[0], v2[1]); qb[1] = cvt_pk(v2[2], v2[3]);
      qb[2] = cvt_pk(v3[0], v3[1]); qb[3] = cvt_pk(v3[2], v3[3]);
      *(u32x4*)hd = qa; *((u32x4*)hd + 1) = qb;
    } else {
      int tp = dir ? t_io + 1 : t_io - 1;
      const u16* p = hout + ((long)(bs * 16 + srow) * 128 + tp) * 256 + scol;
      u32x4 r0, r1; int guard = 0; bool ok;
      do {
        asm volatile(
          "global_load_dwordx4 %0, %2, off sc0 sc1\n\t"
          "global_load_dwordx4 %1, %2, off offset:16 sc0 sc1\n\t"
          "s_waitcnt vmcnt(0)"
          : "=v"(r0), "=v"(r1) : "v"(p) : "memory");
        ok = half_ok(r0[0]) & half_ok(r0[1]) & half_ok(r0[2]) & half_ok(r0[3])
           & half_ok(r1[0]) & half_ok(r1[1]) & half_ok(r1[2]) & half_ok(r1[3]);
      } while (__builtin_expect(!ok, 0) && ++guard < (1 << 22));
      *(u32x4*)hd = r0; *((u32x4*)hd + 1) = r1;
    }
    __syncthreads();
    // ---- MFMA: A = weight fragments, B = x/h fragments -> lane-local gates ----
    bf16x8 hbf[8];
#pragma unroll
    for (int ks = 0; ks < 8; ++ks)
      hbf[ks] = *(const bf16x8*)&hst[cur][lb * LW + ks * 32 + lk8];
    f32x4 acc0 = bv0, acc1 = bv1;
#pragma unroll
    for (int ks = 0; ks < 8; ++ks) {
      int k = ks * 32 + lk8;
      int r0_ = w * 32 + lb, r1_ = r0_ + 16;
      long wi0 = *(const long*)&wli8[r0_ * 264 + k];
      long wi1 = *(const long*)&wli8[r1_ * 264 + k];
      bf16x8 wh0 = *(const bf16x8*)&wlh[r0_ * LW + k];
      bf16x8 wh1 = *(const bf16x8*)&wlh[r1_ * LW + k];
      acc0 = __builtin_amdgcn_mfma_f32_16x16x32_fp8_fp8(wi0, xb[ks], acc0, 0, 0, 0);
      acc0 = __builtin_amdgcn_mfma_f32_16x16x32_bf16(wh0, hbf[ks], acc0, 0, 0, 0);
      acc1 = __builtin_amdgcn_mfma_f32_16x16x32_fp8_fp8(wi1, xb[ks], acc1, 0, 0, 0);
      acc1 = __builtin_amdgcn_mfma_f32_16x16x32_bf16(wh1, hbf[ks], acc1, 0, 0, 0);
    }
    // ---- lane-local epilogue: acc = [i,f,g,o] of (j,b) ----
    long hrow = ((long)b_g * 128 + t_io) * 256;
    {
      float c = sigm(acc0[1]) * cv0 + sigm(acc0[0]) * tanhf_(acc0[2]);
      cv0 = c;
      u16 hv = f2bf(sigm(acc0[3]) * tanhf_(c));
      asm volatile("global_store_short %0, %1, off sc0 sc1"
                   :: "v"(hout + hrow + j0), "v"((unsigned)hv) : "memory");
    }
    {
      float c = sigm(acc1[1]) * cv1 + sigm(acc1[0]) * tanhf_(acc1[2]);
      cv1 = c;
      u16 hv = f2bf(sigm(acc1[3]) * tanhf_(c));
      asm volatile("global_store_short %0, %1, off sc0 sc1"
                   :: "v"(hout + hrow + j1), "v"((unsigned)hv) : "memory");
    }
    // ---- prefetch next step's x fragments (L2-warm; overlaps next poll) ----
    if (sl < 127) {
      int tN = dir ? 126 - sl : sl + 1;
      long xrow = (long)ix[b_g * 128 + tN] * 256;
#pragma unroll
      for (int ks = 0; ks < 8; ++ks) xb[ks] = *(const long*)(eb8 + xrow + ks * 32 + lk8);
    }
    cur ^= 1;
  }
}

// ---------- K3: emission (also zero-inits out[0] for the tail's atomic loss sum) ----------
__global__ __launch_bounds__(256) void k_emis(const u16* __restrict__ hfb, const u16* __restrict__ hbb,
    const u16* __restrict__ weh, const float* __restrict__ bemit, float* __restrict__ emis,
    float* __restrict__ out) {
  if (blockIdx.x == 0 && threadIdx.x == 0) out[0] = 0.f;
  int w = threadIdx.x >> 6, l = threadIdx.x & 63;
  int la = l & 15, lk = (l >> 4) * 8;
  long m0 = (long)blockIdx.x * 64 + w * 16;
  long am = m0 + la;
  f32x4 acc = (f32x4){0.f, 0.f, 0.f, 0.f};
#pragma unroll
  for (int ks = 0; ks < 16; ++ks) {
    int k = ks * 32 + lk;
    const u16* src = (k < 256) ? (hfb + am * 256 + k) : (hbb + am * 256 + (k - 256));
    bf16x8 ah = *(const bf16x8*)src;
    bf16x8 bh = *(const bf16x8*)(weh + la * 512 + k);
    acc = __builtin_amdgcn_mfma_f32_16x16x32_bf16(ah, bh, acc, 0, 0, 0);
  }
  int kout = la;
  float bias = (kout < 9) ? bemit[kout] : 0.f;
  long mr = m0 + (l >> 4) * 4;
#pragma unroll
  for (int r = 0; r < 4; ++r)
    emis[(mr + r) * 16 + kout] = acc[r] + bias;
}

// ---------- K4: fused tail. Blocks 0-15: CRF -> atomicAdd loss. 16-31: Viterbi + backtrace. ----------
__global__ __launch_bounds__(256) void k_tail(const float* __restrict__ emis, const int* __restrict__ ixin,
    const int* __restrict__ label, const float* __restrict__ startt, const float* __restrict__ endt,
    const float* __restrict__ trans, float* __restrict__ out) {
  __shared__ float al_s[16][16];
  __shared__ float tr_s[9][16];
  __shared__ float num_s[16];
  __shared__ float red_s[16];
  __shared__ unsigned char bpl[16 * 127 * 16];
  int tid = threadIdx.x, bl = tid >> 4, k = tid & 15;
  int bid = blockIdx.x;
  if (bl < 9) tr_s[bl][k] = (k < 9) ? trans[bl * 9 + k] : 0.f;
  if (bid < 16) {
    int b = bid * 16 + bl;
    float a = 0.f, num = 0.f;
    int lastlab = 0;
    if (k < 9) a = startt[k] + emis[((long)b * 128) * 16 + k];
    al_s[bl][k] = a;
    if (k == 9) {
      int l0 = label[b * 128];
      num = startt[l0] + emis[((long)b * 128) * 16 + l0];
      lastlab = l0;
    }
    __syncthreads();
    for (int t = 1; t < 128; ++t) {
      bool msk = ixin[b * 128 + t] != 0;
      float anew = a;
      if (k < 9) {
        float mx = -1e30f;
#pragma unroll
        for (int j = 0; j < 9; ++j) mx = fmaxf(mx, al_s[bl][j] + tr_s[j][k]);
        float ss = 0.f;
#pragma unroll
        for (int j = 0; j < 9; ++j) ss += __expf(al_s[bl][j] + tr_s[j][k] - mx);
        anew = mx + __logf(ss) + emis[((long)b * 128 + t) * 16 + k];
        if (!msk) anew = a;
      } else if (k == 9 && msk) {
        int lt = label[b * 128 + t];
        num += tr_s[lastlab][lt] + emis[((long)b * 128 + t) * 16 + lt];
        lastlab = lt;
      }
      __syncthreads();
      if (k < 9) { a = anew; al_s[bl][k] = a; }
      __syncthreads();
    }
    if (k == 9) num_s[bl] = num + endt[lastlab];
    __syncthreads();
    if (k == 0) {
      float mx = -1e30f;
#pragma unroll
      for (int j = 0; j < 9; ++j) mx = fmaxf(mx, al_s[bl][j] + endt[j]);
      float ss = 0.f;
#pragma unroll
      for (int j = 0; j < 9; ++j) ss += __expf(al_s[bl][j] + endt[j] - mx);
      red_s[bl] = (mx + __logf(ss)) - num_s[bl];
    }
    __syncthreads();
    if (tid == 0) {
      float s = 0.f;
      for (int i = 0; i < 16; ++i) s += red_s[i];
      atomicAdd(out, s);
    }
  } else {
    int vb = bid - 16;
    int b = vb * 16 + bl;
    float v = -1e30f;
    if (k < 9) v = startt[k] + emis[((long)b * 128) * 16 + k];
    al_s[bl][k] = v;
    __syncthreads();
    for (int t = 1; t < 128; ++t) {
      float vnew = v;
      if (k < 9) {
        float best = -1e30f; int bi = 0;
#pragma unroll
        for (int j = 0; j < 9; ++j) {
          float tot = al_s[bl][j] + tr_s[j][k];
          if (tot > best) { best = tot; bi = j; }
        }
        vnew = best + emis[((long)b * 128 + t) * 16 + k];
        bpl[(bl * 127 + (t - 1)) * 16 + k] = (unsigned char)bi;
      }
      __syncthreads();
      if (k < 9) { v = vnew; al_s[bl][k] = v; }
      __syncthreads();
    }
    if (tid < 16) {
      int bb = vb * 16 + tid;
      float best = -1e30f; int tag = 0;
#pragma unroll
      for (int j = 0; j < 9; ++j) {
        float vv = al_s[tid][j] + endt[j];
        if (vv > best) { best = vv; tag = j; }
      }
      out[1 + bb * 128 + 127] = (float)tag;
      for (int t = 127; t >= 1; --t) {
        tag = bpl[(tid * 127 + (t - 1)) * 16 + tag];
        out[1 + bb * 128 + t - 1] = (float)tag;
      }
    }
  }
}

__global__ void k_sent(float* out) { out[0] = -1.0e6f; }

// ---------- launch ----------
extern "C" void kernel_launch(void* const* d_in, const int* in_sizes, int n_in,
                              void* d_out, int out_size, void* d_ws, size_t ws_size,
                              hipStream_t stream) {
  const int* in_x    = (const int*)d_in[0];
  const int* label   = (const int*)d_in[1];
  const float* emb   = (const float*)d_in[2];
  const float* Wih_f = (const float*)d_in[3];
  const float* Whh_f = (const float*)d_in[4];
  const float* b_f   = (const float*)d_in[5];
  const float* Wih_b = (const float*)d_in[6];
  const float* Whh_b = (const float*)d_in[7];
  const float* b_b   = (const float*)d_in[8];
  const float* W_emit= (const float*)d_in[9];
  const float* b_emit= (const float*)d_in[10];
  const float* start_t=(const float*)d_in[11];
  const float* end_t = (const float*)d_in[12];
  const float* trans = (const float*)d_in[13];
  const float* h0f   = (const float*)d_in[14];
  const float* c0f   = (const float*)d_in[15];
  const float* h0b   = (const float*)d_in[16];
  const float* c0b   = (const float*)d_in[17];
  (void)in_sizes; (void)n_in; (void)out_size;

  auto align = [](size_t x) { return (x + 255) & ~(size_t)255; };
  char* ws = (char*)d_ws;
  size_t o = 0;
  auto alloc = [&](size_t sz) { size_t r = o; o += (sz + 255) & ~(size_t)255; return r; };
  size_t need = align(32768L * 256 * 2) * 2 + align(30000L * 256) + align(2048L * 256)
              + align(16L * 512 * 2) + align(32768L * 16 * 4);
  if (need > ws_size) { k_sent<<<1, 1, 0, stream>>>((float*)d_out); return; }

  u16* hf    = (u16*)(ws + alloc(32768L * 256 * 2));
  u16* hb    = (u16*)(ws + alloc(32768L * 256 * 2));
  char* eb8  = (char*)(ws + alloc(30000L * 256));
  char* wih8 = (char*)(ws + alloc(2048L * 256));
  u16* weh   = (u16*)(ws + alloc(16L * 512 * 2));
  float* emis= (float*)(ws + alloc(32768L * 16 * 4));

  // sentinel-init h buffers (0xC1C1 bf16 == -24.1, impossible for tanh*sigm output);
  // re-poisoned every call so graph replays never see stale h as "ready".
  hipMemsetAsync(hf, 0xC1, 32768L * 256 * 2, stream);
  hipMemsetAsync(hb, 0xC1, 32768L * 256 * 2, stream);
  k_prep<<<8020, 256, 0, stream>>>(emb, Wih_f, Wih_b, W_emit, eb8, wih8, weh);
  k_lstm<<<256, 256, 0, stream>>>(Whh_f, Whh_b, wih8, eb8, in_x, b_f, b_b,
                                  h0f, c0f, h0b, c0b, hf, hb);
  k_emis<<<512, 256, 0, stream>>>(hf, hb, weh, b_emit, emis, (float*)d_out);
  k_tail<<<32, 256, 0, stream>>>(emis, in_x, label, start_t, end_t, trans, (float*)d_out);
}

// Round 14
// 385.923 us; speedup vs baseline: 1.5710x; 1.5052x over previous
//
#include <hip/hip_runtime.h>

typedef __attribute__((ext_vector_type(8))) short bf16x8;
typedef __attribute__((ext_vector_type(4))) float f32x4;
typedef __attribute__((ext_vector_type(4))) unsigned u32x4;
typedef unsigned short u16;

#define SENT 0xC1C1C1C1u

// ---------- helpers ----------
__device__ __forceinline__ u16 f2bf(float f) {
  union { float f; unsigned u; } v; v.f = f;
  unsigned r = v.u + 0x7fffu + ((v.u >> 16) & 1u);
  return (u16)(r >> 16);
}
__device__ __forceinline__ unsigned cvt_pk(float lo, float hi) {
  unsigned r;
  asm("v_cvt_pk_bf16_f32 %0, %1, %2" : "=v"(r) : "v"(lo), "v"(hi));
  return r;
}
__device__ __forceinline__ float sigm(float x) { return 1.f / (1.f + __expf(-x)); }
__device__ __forceinline__ float tanhf_(float x) { return 1.f - 2.f / (__expf(2.f * x) + 1.f); }
__device__ __forceinline__ int pk4f(float a, float b, float c, float d) {
  int r = __builtin_amdgcn_cvt_pk_fp8_f32(a, b, 0, false);
  return __builtin_amdgcn_cvt_pk_fp8_f32(c, d, r, true);
}

// ---------- K0: one-pass prep: emb -> fp8 eb8 | Wih f,b -> fp8 wih8 | W_emit -> bf16 weh ----------
__global__ __launch_bounds__(256) void k_prep(const float* __restrict__ emb,
    const float* __restrict__ wf, const float* __restrict__ wb, const float* __restrict__ we,
    char* __restrict__ eb8, char* __restrict__ wih8, u16* __restrict__ weh) {
  int i4 = (blockIdx.x * 256 + threadIdx.x) * 4;
  if (i4 < 8204288) {
    const float* src; char* dst; int o;
    if (i4 < 7680000) { src = emb + i4; dst = eb8; o = i4; }
    else { int off = i4 - 7680000;
           src = (off < 262144) ? (wf + off) : (wb + off - 262144);
           dst = wih8; o = off; }
    f32x4 v = *(const f32x4*)src;
    *(int*)(dst + o) = pk4f(v[0], v[1], v[2], v[3]);
  } else {
    int off = i4 - 8204288;          // 0..8191 (W_emit padded to 16 rows)
    int r = off >> 9, k = off & 511;
    f32x4 v = (r < 9) ? *(const f32x4*)(we + r * 512 + k) : (f32x4){0.f, 0.f, 0.f, 0.f};
    *(unsigned*)(weh + off) = cvt_pk(v[0], v[1]);
    *(unsigned*)(weh + off + 2) = cvt_pk(v[2], v[3]);
  }
}

// ---------- K1: fused BiLSTM (input GEMM folded in), sentinel-dataflow cross-block sync ----------
// 256 blocks = 2 dir x 16 batch-slices x 8 j-slices; per block LDS: Whh slice bf16 (67.6K) +
// Wih slice fp8 (33.8K) + h stage (8.4K) + x stage fp8 (4.3K) + gate exchange (8.4K) = 122.6 KB.
// Each block computes its own Wih·x gate-columns (disjoint across j-slices -> no duplicate FLOP).
// Proven round-11 structure: coalesced MALL sentinel polls + packed 4B h-stores. Rounds 12/13
// showed restructurings (chain interleave, lane-local epilogue w/ 2B scattered stores) regress.
#define LW 264
__global__ __launch_bounds__(256) void k_lstm(
    const float* __restrict__ whh_f, const float* __restrict__ whh_b,
    const char* __restrict__ wih8, const char* __restrict__ eb8,
    const int* __restrict__ ix,
    const float* __restrict__ bf_, const float* __restrict__ bb_,
    const float* __restrict__ h0f, const float* __restrict__ c0f,
    const float* __restrict__ h0b, const float* __restrict__ c0b,
    u16* __restrict__ hf, u16* __restrict__ hb) {
  __shared__ u16 wlh[128 * LW];              // Whh slice bf16
  __shared__ char wli8[128 * 264];           // Wih slice fp8
  __shared__ u16 hst[16 * LW];               // h(t-1) stage bf16
  __shared__ __align__(16) char hsa8[16 * 272];  // x(t) stage fp8
  __shared__ float gl[16 * 132];             // gate exchange f32
  int bid = blockIdx.x;
  int js = (bid >> 3) & 7;
  int G = ((bid >> 6) << 3) | (bid & 7);
  int dir = G >> 4, bs = G & 15;
  const float* whh = dir ? whh_b : whh_f;
  u16* hout = dir ? hb : hf;
  int tid = threadIdx.x;
  for (int i = 0; i < 128; ++i) {
    int q = i >> 5, u = i & 31;
    int gate = q * 256 + js * 32 + u;
    wlh[i * LW + tid] = f2bf(whh[gate * 256 + tid]);
    wli8[i * 264 + tid] = wih8[(dir * 1024 + gate) * 256 + tid];
  }
  int b_l = tid >> 4, jj = tid & 15;
  int b_g = bs * 16 + b_l;
  int jg0 = js * 32 + jj * 2;
  // biases
  const float* bsrc = dir ? bb_ : bf_;
  float bI0 = bsrc[jg0],       bI1 = bsrc[jg0 + 1];
  float bF0 = bsrc[256 + jg0], bF1 = bsrc[257 + jg0];
  float bG0 = bsrc[512 + jg0], bG1 = bsrc[513 + jg0];
  float bO0 = bsrc[768 + jg0], bO1 = bsrc[769 + jg0];
  const float* c0 = dir ? c0b : c0f;
  float cv0 = c0[b_g * 256 + jg0];
  float cv1 = c0[b_g * 256 + jg0 + 1];
  int w = tid >> 6, l = tid & 63, la = l & 15, lk = (l >> 4) * 8;
  int srow = tid >> 4, scol = (tid & 15) * 16;
  const float* h0 = dir ? h0b : h0f;
  const int* ixrow = ix + (bs * 16 + srow) * 128;
  // prefetch x-row for step 0
  u32x4 aR;
  {
    int tA = dir ? 127 : 0;
    const char* ap = eb8 + (long)ixrow[tA] * 256 + scol;
    aR = *(const u32x4*)ap;
  }
  __syncthreads();
  for (int sl = 0; sl < 128; ++sl) {
    int t_io = dir ? 127 - sl : sl;
    // stage x(t) (prefetched last iteration)
    *(u32x4*)&hsa8[srow * 272 + scol] = aR;
    // stage h(t-1)
    u16* hd = &hst[srow * LW + scol];
    if (sl == 0) {
      const float* p = h0 + (bs * 16 + srow) * 256 + scol;
      f32x4 v0 = *(const f32x4*)p, v1 = *(const f32x4*)(p + 4);
      f32x4 v2 = *(const f32x4*)(p + 8), v3 = *(const f32x4*)(p + 12);
      u32x4 qa, qb;
      qa[0] = cvt_pk(v0[0], v0[1]); qa[1] = cvt_pk(v0[2], v0[3]);
      qa[2] = cvt_pk(v1[0], v1[1]); qa[3] = cvt_pk(v1[2], v1[3]);
      qb[0] = cvt_pk(v2[0], v2[1]); qb[1] = cvt_pk(v2[2], v2[3]);
      qb[2] = cvt_pk(v3[0], v3[1]); qb[3] = cvt_pk(v3[2], v3[3]);
      *(u32x4*)hd = qa; *((u32x4*)hd + 1) = qb;
    } else {
      int tp = dir ? t_io + 1 : t_io - 1;
      const u16* p = hout + ((long)(bs * 16 + srow) * 128 + tp) * 256 + scol;
      u32x4 r0, r1; int guard = 0; bool ok;
      do {
        asm volatile(
          "global_load_dwordx4 %0, %2, off sc0 sc1\n\t"
          "global_load_dwordx4 %1, %2, off offset:16 sc0 sc1\n\t"
          "s_waitcnt vmcnt(0)"
          : "=v"(r0), "=v"(r1) : "v"(p) : "memory");
        ok = (r0[0] != SENT) & (r0[1] != SENT) & (r0[2] != SENT) & (r0[3] != SENT)
           & (r1[0] != SENT) & (r1[1] != SENT) & (r1[2] != SENT) & (r1[3] != SENT);
      } while (__builtin_expect(!ok, 0) && ++guard < (1 << 22));
      *(u32x4*)hd = r0; *((u32x4*)hd + 1) = r1;
    }
    __syncthreads();
    // ---- MFMA: gates = Wih·x + Whh·h for this block's 2x16 gate rows ----
    f32x4 a0 = (f32x4){0.f, 0.f, 0.f, 0.f}, a1 = (f32x4){0.f, 0.f, 0.f, 0.f};
#pragma unroll
    for (int ks = 0; ks < 8; ++ks) {
      int k = ks * 32 + lk;
      long xv = *(const long*)&hsa8[la * 272 + k];
      bf16x8 hh = *(const bf16x8*)&hst[la * LW + k];
      int r0_ = w * 32 + la, r1_ = w * 32 + 16 + la;
      long wi0 = *(const long*)&wli8[r0_ * 264 + k];
      long wi1 = *(const long*)&wli8[r1_ * 264 + k];
      bf16x8 wh0 = *(const bf16x8*)&wlh[r0_ * LW + k];
      bf16x8 wh1 = *(const bf16x8*)&wlh[r1_ * LW + k];
      a0 = __builtin_amdgcn_mfma_f32_16x16x32_fp8_fp8(xv, wi0, a0, 0, 0, 0);
      a0 = __builtin_amdgcn_mfma_f32_16x16x32_bf16(hh, wh0, a0, 0, 0, 0);
      a1 = __builtin_amdgcn_mfma_f32_16x16x32_fp8_fp8(xv, wi1, a1, 0, 0, 0);
      a1 = __builtin_amdgcn_mfma_f32_16x16x32_bf16(hh, wh1, a1, 0, 0, 0);
    }
#pragma unroll
    for (int r = 0; r < 4; ++r) {
      gl[((l >> 4) * 4 + r) * 132 + w * 32 + la] = a0[r];
      gl[((l >> 4) * 4 + r) * 132 + w * 32 + 16 + la] = a1[r];
    }
    __syncthreads();
    float hv0, hv1;
    {
      int jl = jj * 2;
      float gi = gl[b_l * 132 + jl]      + bI0;
      float gf = gl[b_l * 132 + 32 + jl] + bF0;
      float gg = gl[b_l * 132 + 64 + jl] + bG0;
      float go = gl[b_l * 132 + 96 + jl] + bO0;
      float c = sigm(gf) * cv0 + sigm(gi) * tanhf_(gg);
      cv0 = c; hv0 = sigm(go) * tanhf_(c);
    }
    {
      int jl = jj * 2 + 1;
      float gi = gl[b_l * 132 + jl]      + bI1;
      float gf = gl[b_l * 132 + 32 + jl] + bF1;
      float gg = gl[b_l * 132 + 64 + jl] + bG1;
      float go = gl[b_l * 132 + 96 + jl] + bO1;
      float c = sigm(gf) * cv1 + sigm(gi) * tanhf_(gg);
      cv1 = c; hv1 = sigm(go) * tanhf_(c);
    }
    unsigned pk = cvt_pk(hv0, hv1);
    __hip_atomic_store((unsigned*)(hout + ((long)b_g * 128 + t_io) * 256 + jg0), pk,
                       __ATOMIC_RELAXED, __HIP_MEMORY_SCOPE_AGENT);
    // prefetch next step's x-row (completes during next poll)
    if (sl < 127) {
      int tN = dir ? 126 - sl : sl + 1;
      const char* ap = eb8 + (long)ixrow[tN] * 256 + scol;
      aR = *(const u32x4*)ap;
    }
  }
}

// ---------- K3: emission (also zero-inits out[0] for the tail's atomic loss sum) ----------
__global__ __launch_bounds__(256) void k_emis(const u16* __restrict__ hfb, const u16* __restrict__ hbb,
    const u16* __restrict__ weh, const float* __restrict__ bemit, float* __restrict__ emis,
    float* __restrict__ out) {
  if (blockIdx.x == 0 && threadIdx.x == 0) out[0] = 0.f;
  int w = threadIdx.x >> 6, l = threadIdx.x & 63;
  int la = l & 15, lk = (l >> 4) * 8;
  long m0 = (long)blockIdx.x * 64 + w * 16;
  long am = m0 + la;
  f32x4 acc = (f32x4){0.f, 0.f, 0.f, 0.f};
#pragma unroll
  for (int ks = 0; ks < 16; ++ks) {
    int k = ks * 32 + lk;
    const u16* src = (k < 256) ? (hfb + am * 256 + k) : (hbb + am * 256 + (k - 256));
    bf16x8 ah = *(const bf16x8*)src;
    bf16x8 bh = *(const bf16x8*)(weh + la * 512 + k);
    acc = __builtin_amdgcn_mfma_f32_16x16x32_bf16(ah, bh, acc, 0, 0, 0);
  }
  int kout = la;
  float bias = (kout < 9) ? bemit[kout] : 0.f;
  long mr = m0 + (l >> 4) * 4;
#pragma unroll
  for (int r = 0; r < 4; ++r)
    emis[(mr + r) * 16 + kout] = acc[r] + bias;
}

// ---------- K4: fused tail. Blocks 0-15: CRF -> atomicAdd loss. 16-31: Viterbi + backtrace. ----------
__global__ __launch_bounds__(256) void k_tail(const float* __restrict__ emis, const int* __restrict__ ixin,
    const int* __restrict__ label, const float* __restrict__ startt, const float* __restrict__ endt,
    const float* __restrict__ trans, float* __restrict__ out) {
  __shared__ float al_s[16][16];
  __shared__ float tr_s[9][16];
  __shared__ float num_s[16];
  __shared__ float red_s[16];
  __shared__ unsigned char bpl[16 * 127 * 16];
  int tid = threadIdx.x, bl = tid >> 4, k = tid & 15;
  int bid = blockIdx.x;
  if (bl < 9) tr_s[bl][k] = (k < 9) ? trans[bl * 9 + k] : 0.f;
  if (bid < 16) {
    int b = bid * 16 + bl;
    float a = 0.f, num = 0.f;
    int lastlab = 0;
    if (k < 9) a = startt[k] + emis[((long)b * 128) * 16 + k];
    al_s[bl][k] = a;
    if (k == 9) {
      int l0 = label[b * 128];
      num = startt[l0] + emis[((long)b * 128) * 16 + l0];
      lastlab = l0;
    }
    __syncthreads();
    for (int t = 1; t < 128; ++t) {
      bool msk = ixin[b * 128 + t] != 0;
      float anew = a;
      if (k < 9) {
        float mx = -1e30f;
#pragma unroll
        for (int j = 0; j < 9; ++j) mx = fmaxf(mx, al_s[bl][j] + tr_s[j][k]);
        float ss = 0.f;
#pragma unroll
        for (int j = 0; j < 9; ++j) ss += __expf(al_s[bl][j] + tr_s[j][k] - mx);
        anew = mx + __logf(ss) + emis[((long)b * 128 + t) * 16 + k];
        if (!msk) anew = a;
      } else if (k == 9 && msk) {
        int lt = label[b * 128 + t];
        num += tr_s[lastlab][lt] + emis[((long)b * 128 + t) * 16 + lt];
        lastlab = lt;
      }
      __syncthreads();
      if (k < 9) { a = anew; al_s[bl][k] = a; }
      __syncthreads();
    }
    if (k == 9) num_s[bl] = num + endt[lastlab];
    __syncthreads();
    if (k == 0) {
      float mx = -1e30f;
#pragma unroll
      for (int j = 0; j < 9; ++j) mx = fmaxf(mx, al_s[bl][j] + endt[j]);
      float ss = 0.f;
#pragma unroll
      for (int j = 0; j < 9; ++j) ss += __expf(al_s[bl][j] + endt[j] - mx);
      red_s[bl] = (mx + __logf(ss)) - num_s[bl];
    }
    __syncthreads();
    if (tid == 0) {
      float s = 0.f;
      for (int i = 0; i < 16; ++i) s += red_s[i];
      atomicAdd(out, s);
    }
  } else {
    int vb = bid - 16;
    int b = vb * 16 + bl;
    float v = -1e30f;
    if (k < 9) v = startt[k] + emis[((long)b * 128) * 16 + k];
    al_s[bl][k] = v;
    __syncthreads();
    for (int t = 1; t < 128; ++t) {
      float vnew = v;
      if (k < 9) {
        float best = -1e30f; int bi = 0;
#pragma unroll
        for (int j = 0; j < 9; ++j) {
          float tot = al_s[bl][j] + tr_s[j][k];
          if (tot > best) { best = tot; bi = j; }
        }
        vnew = best + emis[((long)b * 128 + t) * 16 + k];
        bpl[(bl * 127 + (t - 1)) * 16 + k] = (unsigned char)bi;
      }
      __syncthreads();
      if (k < 9) { v = vnew; al_s[bl][k] = v; }
      __syncthreads();
    }
    if (tid < 16) {
      int bb = vb * 16 + tid;
      float best = -1e30f; int tag = 0;
#pragma unroll
      for (int j = 0; j < 9; ++j) {
        float vv = al_s[tid][j] + endt[j];
        if (vv > best) { best = vv; tag = j; }
      }
      out[1 + bb * 128 + 127] = (float)tag;
      for (int t = 127; t >= 1; --t) {
        tag = bpl[(tid * 127 + (t - 1)) * 16 + tag];
        out[1 + bb * 128 + t - 1] = (float)tag;
      }
    }
  }
}

__global__ void k_sent(float* out) { out[0] = -1.0e6f; }

// ---------- launch ----------
extern "C" void kernel_launch(void* const* d_in, const int* in_sizes, int n_in,
                              void* d_out, int out_size, void* d_ws, size_t ws_size,
                              hipStream_t stream) {
  const int* in_x    = (const int*)d_in[0];
  const int* label   = (const int*)d_in[1];
  const float* emb   = (const float*)d_in[2];
  const float* Wih_f = (const float*)d_in[3];
  const float* Whh_f = (const float*)d_in[4];
  const float* b_f   = (const float*)d_in[5];
  const float* Wih_b = (const float*)d_in[6];
  const float* Whh_b = (const float*)d_in[7];
  const float* b_b   = (const float*)d_in[8];
  const float* W_emit= (const float*)d_in[9];
  const float* b_emit= (const float*)d_in[10];
  const float* start_t=(const float*)d_in[11];
  const float* end_t = (const float*)d_in[12];
  const float* trans = (const float*)d_in[13];
  const float* h0f   = (const float*)d_in[14];
  const float* c0f   = (const float*)d_in[15];
  const float* h0b   = (const float*)d_in[16];
  const float* c0b   = (const float*)d_in[17];
  (void)in_sizes; (void)n_in; (void)out_size;

  auto align = [](size_t x) { return (x + 255) & ~(size_t)255; };
  char* ws = (char*)d_ws;
  size_t o = 0;
  auto alloc = [&](size_t sz) { size_t r = o; o += (sz + 255) & ~(size_t)255; return r; };
  size_t need = align(32768L * 256 * 2) * 2 + align(30000L * 256) + align(2048L * 256)
              + align(16L * 512 * 2) + align(32768L * 16 * 4);
  if (need > ws_size) { k_sent<<<1, 1, 0, stream>>>((float*)d_out); return; }

  u16* hf    = (u16*)(ws + alloc(32768L * 256 * 2));
  u16* hb    = (u16*)(ws + alloc(32768L * 256 * 2));
  char* eb8  = (char*)(ws + alloc(30000L * 256));
  char* wih8 = (char*)(ws + alloc(2048L * 256));
  u16* weh   = (u16*)(ws + alloc(16L * 512 * 2));
  float* emis= (float*)(ws + alloc(32768L * 16 * 4));

  // sentinel-init h buffers (0xC1C1 bf16 == -24.1, impossible for tanh*sigm output);
  // re-poisoned every call so graph replays never see stale h as "ready".
  hipMemsetAsync(hf, 0xC1, 32768L * 256 * 2, stream);
  hipMemsetAsync(hb, 0xC1, 32768L * 256 * 2, stream);
  k_prep<<<8020, 256, 0, stream>>>(emb, Wih_f, Wih_b, W_emit, eb8, wih8, weh);
  k_lstm<<<256, 256, 0, stream>>>(Whh_f, Whh_b, wih8, eb8, in_x, b_f, b_b,
                                  h0f, c0f, h0b, c0b, hf, hb);
  k_emis<<<512, 256, 0, stream>>>(hf, hb, weh, b_emit, emis, (float*)d_out);
  k_tail<<<32, 256, 0, stream>>>(emis, in_x, label, start_t, end_t, trans, (float*)d_out);
}